// Round 11
// baseline (195.859 us; speedup 1.0000x reference)
//
#include <hip/hip_runtime.h>
#include <hip/hip_bf16.h>
#include <math.h>

#define N_ROWS 65536
#define PSI    1024
#define DDIM   256

typedef _Float16       half8 __attribute__((ext_vector_type(8)));
typedef _Float16       half4 __attribute__((ext_vector_type(4)));
typedef float          f32x4 __attribute__((ext_vector_type(4)));

// ---------- async global->LDS, 16B per lane ----------
__device__ __forceinline__ void gload16(const void* g, void* l) {
    __builtin_amdgcn_global_load_lds(
        (const __attribute__((address_space(1))) unsigned int*)g,
        (__attribute__((address_space(3))) unsigned int*)l, 16, 0, 0);
}

// ---------- convert f32 -> f16 + row squared-norms, for S only ----------
__global__ __launch_bounds__(256) void k_convert(
    const float* __restrict__ in, _Float16* __restrict__ outh,
    float* __restrict__ nrm, int rows)
{
    const int wave = (blockIdx.x * blockDim.x + threadIdx.x) >> 6;
    const int lane = threadIdx.x & 63;
    if (wave >= rows) return;
    const float4 v = *(const float4*)&in[(size_t)wave * DDIM + lane * 4];
    float s = v.x * v.x + v.y * v.y + v.z * v.z + v.w * v.w;
    #pragma unroll
    for (int o = 32; o > 0; o >>= 1) s += __shfl_down(s, o);
    if (lane == 0) nrm[wave] = s;
    half4 h;
    h[0] = (_Float16)v.x; h[1] = (_Float16)v.y;
    h[2] = (_Float16)v.z; h[3] = (_Float16)v.w;
    *(half4*)&outh[(size_t)wave * DDIM + lane * 4] = h;
}

// ---------- MFMA GEMM, 128x128 tile, B staged once (full K), A reg-staged --
// X read in f32 directly (no convert pass): per tile each thread loads 4x
// f32x4, casts to f16 in-register (RNE), ds_write_b128 into the swizzled
// A-tile, and accumulates row-norm partials (x2 computed inline, f32-exact
// over X). B[128][256] f16 staged once via gload16 with pre-swizzled global
// chunks (chunk ^= row&15, both-sides). A dbuf 2x8KB, swizzle chunk ^=
// (row>>1)&3 (write-side + read-side). One barrier per K-iter with ZERO
// outstanding vmem at the barrier (A loads for t+2 issued after it).
// Shift-free softmax: u = exp(-m) in [1e-13,1] -> no max-shift needed.
// XCD-chunked 1D grid (4096). LDS 80KB -> 2 blocks/CU.
// MODE 0: per-128-row-band column partial sums of u -> ps
// MODE 1: out = u * rs[c]  (nontemporal stream)
template<int MODE>
__global__ __launch_bounds__(256, 2) void k_gemm(
    const float* __restrict__ X, const _Float16* __restrict__ Sh,
    const float* __restrict__ s2, const float* __restrict__ w,
    float* __restrict__ ps, const float* __restrict__ rs,
    float* __restrict__ out)
{
    __shared__ _Float16 Bs[128 * 256];     // 64 KB, staged once
    __shared__ _Float16 As[2][128 * 32];   // 2 x 8 KB double buffer

    const int tid = threadIdx.x;
    const int wv  = tid >> 6;
    const int l   = tid & 63;
    const int wr  = wv >> 1;        // wave row half
    const int wc  = wv & 1;         // wave col half
    const int l15 = tid & 15;
    const int l4  = (tid & 63) >> 4;

    // XCD swizzle (nwg=4096 divisible by 8 -> bijective)
    const int fid  = blockIdx.x;
    const int wgid = (fid & 7) * 512 + (fid >> 3);
    const int rowb = wgid >> 3;
    const int row0 = rowb * 128;
    const int col0 = (wgid & 7) * 128;

    f32x4 acc[4][4];
    #pragma unroll
    for (int i = 0; i < 4; ++i)
        #pragma unroll
        for (int j = 0; j < 4; ++j) acc[i][j] = (f32x4){0.f, 0.f, 0.f, 0.f};

    // ---- stage B once: 16 gload16 per wave, 64 KB total ----
    #pragma unroll
    for (int i = 0; i < 16; ++i) {
        const int slot = wv * 16 + i;          // wave-uniform LDS base slot
        const int brow = 2 * slot + (l >> 5);  // per-lane row
        const int bch  = (l & 31) ^ (brow & 15);
        gload16(Sh + (size_t)(col0 + brow) * DDIM + bch * 8,
                (char*)Bs + slot * 1024);
    }

    // ---- A reg-staging ----
    const int srow = tid >> 2;                  // 0..63
    const int och  = tid & 3;                   // 16B chunk in 64B row
    const int c0   = och ^ ((srow >> 1) & 3);   // swizzled chunk (same for srow+64)
    const float* gA0 = X + (size_t)(row0 + srow) * DDIM + och * 8;
    const float* gA1 = X + (size_t)(row0 + srow + 64) * DDIM + och * 8;
    float ss0 = 0.f, ss1 = 0.f;

    f32x4 r[2][4];
    auto loadA = [&](int t) {                   // t compile-time (unrolled)
        f32x4* rr = r[t & 1];
        rr[0] = *(const f32x4*)(gA0 + t * 32);
        rr[1] = *(const f32x4*)(gA0 + t * 32 + 4);
        rr[2] = *(const f32x4*)(gA1 + t * 32);
        rr[3] = *(const f32x4*)(gA1 + t * 32 + 4);
    };
    auto writeA = [&](int t) {
        f32x4* rr = r[t & 1];
        half8 h0, h1;
        #pragma unroll
        for (int j = 0; j < 4; ++j) {
            h0[j]     = (_Float16)rr[0][j]; h0[4 + j] = (_Float16)rr[1][j];
            h1[j]     = (_Float16)rr[2][j]; h1[4 + j] = (_Float16)rr[3][j];
            ss0 += rr[0][j] * rr[0][j] + rr[1][j] * rr[1][j];
            ss1 += rr[2][j] * rr[2][j] + rr[3][j] * rr[3][j];
        }
        const int b = t & 1;
        *(half8*)&As[b][srow * 32 + c0 * 8]        = h0;
        *(half8*)&As[b][(srow + 64) * 32 + c0 * 8] = h1;
    };
    auto compute = [&](int t) {
        half8 af[4], bf[4];
        #pragma unroll
        for (int f = 0; f < 4; ++f) {
            const int ra = wr * 64 + f * 16 + l15;
            const int rb = wc * 64 + f * 16 + l15;
            af[f] = *(const half8*)&As[t & 1][(ra * 32 + l4 * 8) ^ ((((ra >> 1) & 3)) << 3)];
            bf[f] = *(const half8*)&Bs[rb * 256 + (((t * 4 + l4) ^ (rb & 15)) << 3)];
        }
        __builtin_amdgcn_s_setprio(1);
        #pragma unroll
        for (int fm = 0; fm < 4; ++fm)
            #pragma unroll
            for (int fn = 0; fn < 4; ++fn)
                acc[fm][fn] = __builtin_amdgcn_mfma_f32_16x16x32_f16(
                    af[fm], bf[fn], acc[fm][fn], 0, 0, 0);
        __builtin_amdgcn_s_setprio(0);
    };

    loadA(0);
    loadA(1);
    writeA(0);
    __syncthreads();                 // B + A0 in LDS
    #pragma unroll
    for (int t = 0; t < 8; ++t) {    // K = 8 x 32
        compute(t);
        if (t < 7) {
            writeA(t + 1);           // regs loaded >=1 compute-phase ago
            __syncthreads();         // zero outstanding vmem here
            if (t < 6) loadA(t + 2); // issue after barrier -> never drained
        }
    }

    // ---- x2 reduce (As[0] dead after compute(6)'s barrier) ----
    float* xp = (float*)&As[0][0];            // [128][4] f32 partials
    xp[srow * 4 + och]        = ss0;
    xp[(srow + 64) * 4 + och] = ss1;
    __syncthreads();

    float x2v[4][4];
    #pragma unroll
    for (int fm = 0; fm < 4; ++fm)
        #pragma unroll
        for (int j = 0; j < 4; ++j) {
            const int rr_ = wr * 64 + fm * 16 + l4 * 4 + j;
            f32x4 p = *(const f32x4*)&xp[rr_ * 4];
            x2v[fm][j] = p[0] + p[1] + p[2] + p[3];
        }

    if (MODE == 0) {
        float* s_sm = (float*)&Bs[0];          // Bs dead now
        __syncthreads();
        if (tid < 128) s_sm[tid] = 0.0f;
        __syncthreads();
        #pragma unroll
        for (int fn = 0; fn < 4; ++fn) {
            const int cl = wc * 64 + fn * 16 + l15;
            const int c  = col0 + cl;
            const float s2c = s2[c], ww = w[c];
            float s = 0.0f;
            #pragma unroll
            for (int fm = 0; fm < 4; ++fm)
                #pragma unroll
                for (int j = 0; j < 4; ++j) {
                    float d2 = x2v[fm][j] + s2c - 2.0f * acc[fm][fn][j];
                    s += __expf(-sqrtf(fmaxf(d2, 0.0f)) * ww);
                }
            s += __shfl_xor(s, 16);
            s += __shfl_xor(s, 32);
            if (l4 == 0) atomicAdd(&s_sm[cl], s);
        }
        __syncthreads();
        if (tid < 128) ps[(size_t)rowb * PSI + col0 + tid] = s_sm[tid];
    } else {
        #pragma unroll
        for (int fn = 0; fn < 4; ++fn) {
            const int c = col0 + wc * 64 + fn * 16 + l15;
            const float s2c = s2[c], ww = w[c];
            const float rsc = rs[c];
            #pragma unroll
            for (int fm = 0; fm < 4; ++fm) {
                const int rbase = row0 + wr * 64 + fm * 16 + l4 * 4;
                #pragma unroll
                for (int j = 0; j < 4; ++j) {
                    float d2 = x2v[fm][j] + s2c - 2.0f * acc[fm][fn][j];
                    float u  = __expf(-sqrtf(fmaxf(d2, 0.0f)) * ww) * rsc;
                    __builtin_nontemporal_store(u, &out[(size_t)(rbase + j) * PSI + c]);
                }
            }
        }
    }
}

// ---------- combine stage 1: 8 chunks x 64 bands, 32 blocks ----------
__global__ __launch_bounds__(256) void k_combine1(
    const float* __restrict__ ps, float* __restrict__ ps2)
{
    const int g     = blockIdx.x * 256 + threadIdx.x;   // [0, 8192)
    const int col   = g & 1023;
    const int chunk = g >> 10;                          // [0, 8)
    const int b0    = chunk * 64;
    float t = 0.0f;
    #pragma unroll 4
    for (int b = 0; b < 64; ++b)
        t += ps[(size_t)(b0 + b) * PSI + col];
    ps2[(size_t)chunk * PSI + col] = t;
}

// ---------- combine stage 2: rs = 1 / total sum ----------
__global__ __launch_bounds__(256) void k_combine2(
    const float* __restrict__ ps2, float* __restrict__ rs)
{
    const int col = blockIdx.x * 256 + threadIdx.x;   // grid 4
    float t = 0.0f;
    #pragma unroll
    for (int b = 0; b < 8; ++b)
        t += ps2[(size_t)b * PSI + col];
    rs[col] = 1.0f / t;
}

extern "C" void kernel_launch(void* const* d_in, const int* in_sizes, int n_in,
                              void* d_out, int out_size, void* d_ws, size_t ws_size,
                              hipStream_t stream) {
    const float* X = (const float*)d_in[0];
    const float* S = (const float*)d_in[1];
    const float* w = (const float*)d_in[2];
    float* out = (float*)d_out;

    char* ws = (char*)d_ws;
    _Float16* Sh  = (_Float16*)(ws);                   //    524,288 B
    float*    s2  = (float*)   (ws + 524288);          //      4,096 B
    float*    ps  = (float*)   (ws + 528384);          //  2,097,152 B
    float*    ps2 = (float*)   (ws + 2625536);         //     32,768 B
    float*    rs  = (float*)   (ws + 2658304);         //      4,096 B

    k_convert<<<dim3(PSI / 4), dim3(256), 0, stream>>>(S, Sh, s2, PSI);
    k_gemm<0><<<dim3(4096), dim3(256), 0, stream>>>(
        X, Sh, s2, w, ps, nullptr, nullptr);
    k_combine1<<<dim3(32), dim3(256), 0, stream>>>(ps, ps2);
    k_combine2<<<dim3(PSI / 256), dim3(256), 0, stream>>>(ps2, rs);
    k_gemm<1><<<dim3(4096), dim3(256), 0, stream>>>(
        X, Sh, s2, w, nullptr, rs, out);
}